// Round 6
// baseline (620.217 us; speedup 1.0000x reference)
//
#include <hip/hip_runtime.h>

#define N_NODES 100000
#define N_EDGES 1600000
#define D 128
#define NBUCK 98          // ceil(N_NODES / 1024), bucket = dst >> 10
#define CAP 20480         // ebuf slab capacity per bucket (raw edges); mean 16384, sigma~127

typedef __attribute__((ext_vector_type(8))) short bf16x8;
typedef __attribute__((ext_vector_type(4))) float f32x4;
typedef unsigned long long u64;

__device__ __forceinline__ float b2f_lo(unsigned int u) {
    return __builtin_bit_cast(float, u << 16);
}
__device__ __forceinline__ float b2f_hi(unsigned int u) {
    return __builtin_bit_cast(float, u & 0xFFFF0000u);
}
__device__ __forceinline__ unsigned short f2b(float f) {
    unsigned int u = __builtin_bit_cast(unsigned int, f);
    u += 0x7FFFu + ((u >> 16) & 1u);
    return (unsigned short)(u >> 16);
}

// ---------------- prep: zero scratch + convert weights + convert x (row-major) ----------------

__global__ __launch_bounds__(256) void prep_kernel(
    const float* __restrict__ x, unsigned short* __restrict__ xb,
    const float* __restrict__ W0, const float* __restrict__ W1_, const float* __restrict__ W2_,
    const float* __restrict__ W3, const float* __restrict__ W4, const float* __restrict__ W5,
    unsigned short* __restrict__ T0, unsigned short* __restrict__ T1_,
    unsigned short* __restrict__ T2_, unsigned short* __restrict__ T3,
    unsigned short* __restrict__ T4, unsigned short* __restrict__ T5,
    uint4* __restrict__ dob4, uint4* __restrict__ xs0, uint4* __restrict__ xs1) {
    int blk = blockIdx.x;
    if (blk < 384) {
        const float* W;
        unsigned short* T;
        switch (blk >> 6) {
            case 0: W = W0; T = T0; break;
            case 1: W = W1_; T = T1_; break;
            case 2: W = W2_; T = T2_; break;
            case 3: W = W3; T = T3; break;
            case 4: W = W4; T = T4; break;
            default: W = W5; T = T5; break;
        }
        int i = (blk & 63) * 256 + threadIdx.x;   // 0..16383
        int k = i >> 7, n = i & 127;
        T[n * 128 + k] = f2b(W[i]);               // [k][n] fp32 -> [n][k] bf16
    } else if (blk < 12884) {
        int i = (blk - 384) * 256 + threadIdx.x;  // float4 chunks, 3,200,000 total
        if (i < 3200000) {
            float4 v = ((const float4*)x)[i];
            ushort4 o;
            o.x = f2b(v.x); o.y = f2b(v.y); o.z = f2b(v.z); o.w = f2b(v.w);
            ((ushort4*)xb)[i] = o;
        }
    } else {
        int i = (blk - 12884) * 256 + threadIdx.x;
        uint4 z = {0u, 0u, 0u, 0u};
        if (i < 256) dob4[i] = z;                 // zero d_out scratch head (bcur)
        if (i < 16) { xs0[i] = z; xs1[i] = z; }   // zero sentinel rows of both buffers
    }
}

// ---------------- CSR build (bucket-local, LDS atomics only, degrees padded to %4) ----------------

__global__ __launch_bounds__(256) void bin_kernel(const int* __restrict__ src,
                                                  const int* __restrict__ dst,
                                                  int* __restrict__ bcur,
                                                  u64* __restrict__ ebuf) {
    __shared__ int h[NBUCK];
    __shared__ int base[NBUCK];
    int tid = threadIdx.x;
    if (tid < NBUCK) h[tid] = 0;
    __syncthreads();
    int e0 = blockIdx.x * 2048;
    int myd[8], mys[8];
#pragma unroll
    for (int i = 0; i < 8; i++) {
        int e = e0 + tid + i * 256;
        int dv = (e < N_EDGES) ? dst[e] : -1;
        myd[i] = dv;
        mys[i] = (e < N_EDGES) ? src[e] : 0;
        if (dv >= 0) atomicAdd(&h[dv >> 10], 1);
    }
    __syncthreads();
    if (tid < NBUCK) {
        int c = h[tid];
        base[tid] = (c > 0) ? (tid * CAP + atomicAdd(&bcur[tid], c)) : 0;
        h[tid] = 0;
    }
    __syncthreads();
#pragma unroll
    for (int i = 0; i < 8; i++) {
        int dv = myd[i];
        if (dv >= 0) {
            int b = dv >> 10;
            int p = base[b] + atomicAdd(&h[b], 1);
            if (p < (b + 1) * CAP)
                ebuf[p] = ((u64)(unsigned int)dv << 32) | (unsigned int)mys[i];
        }
    }
}

__global__ __launch_bounds__(1024) void bucket_hist_kernel(const u64* __restrict__ ebuf,
                                                           const int* __restrict__ bcur,
                                                           int* __restrict__ deg,
                                                           int* __restrict__ ptot) {
    __shared__ int hist[1024];
    int b = blockIdx.x, tid = threadIdx.x;
    int nE = bcur[b]; if (nE > CAP) nE = CAP;
    const u64* slab = ebuf + (size_t)b * CAP;
    hist[tid] = 0;
    __syncthreads();
    for (int i = tid; i < nE; i += 1024)
        atomicAdd(&hist[(int)(slab[i] >> 32) & 1023], 1);
    __syncthreads();
    int node = b * 1024 + tid;
    int d = hist[tid];
    if (node < N_NODES) deg[node] = d;
    int dp = (node < N_NODES) ? ((d + 3) & ~3) : 0;
    __syncthreads();
    hist[tid] = dp;
    __syncthreads();
#pragma unroll
    for (int s = 512; s > 0; s >>= 1) {
        if (tid < s) hist[tid] += hist[tid + s];
        __syncthreads();
    }
    if (tid == 0) ptot[b] = hist[0];
}

__global__ __launch_bounds__(128) void pscan_kernel(const int* __restrict__ ptot,
                                                    int* __restrict__ bbase,
                                                    int* __restrict__ off) {
    __shared__ int s[128];
    int tid = threadIdx.x;
    int v = (tid < NBUCK) ? ptot[tid] : 0;
    s[tid] = v;
    __syncthreads();
#pragma unroll
    for (int d = 1; d < 128; d <<= 1) {
        int t = (tid >= d) ? s[tid - d] : 0;
        __syncthreads();
        s[tid] += t;
        __syncthreads();
    }
    if (tid < NBUCK) bbase[tid] = s[tid] - v;
    if (tid == 127) off[N_NODES] = s[127];
}

__global__ __launch_bounds__(1024) void bucket_csr_kernel(const u64* __restrict__ ebuf,
                                                          const int* __restrict__ bcur,
                                                          const int* __restrict__ deg,
                                                          const int* __restrict__ bbase,
                                                          int* __restrict__ off,
                                                          int* __restrict__ csr) {
    __shared__ int sc[1024];
    __shared__ int cnt[1024];
    int b = blockIdx.x, tid = threadIdx.x;
    int nE = bcur[b]; if (nE > CAP) nE = CAP;
    int base = bbase[b];
    const u64* slab = ebuf + (size_t)b * CAP;
    int node = b * 1024 + tid;
    int d = (node < N_NODES) ? deg[node] : 0;
    int dp = (node < N_NODES) ? ((d + 3) & ~3) : 0;
    sc[tid] = dp;
    cnt[tid] = 0;
    __syncthreads();
#pragma unroll
    for (int s = 1; s < 1024; s <<= 1) {
        int t = (tid >= s) ? sc[tid - s] : 0;
        __syncthreads();
        sc[tid] += t;
        __syncthreads();
    }
    int excl = sc[tid] - dp;
    sc[tid] = excl;
    if (node < N_NODES) off[node] = base + excl;
    __syncthreads();
    for (int i = tid; i < nE; i += 1024) {
        u64 e = slab[i];
        int dd = (int)(e >> 32) & 1023;
        int pos = sc[dd] + atomicAdd(&cnt[dd], 1);
        csr[base + pos] = (int)(e & 0xFFFFFFFFu);
    }
    for (int j = d; j < dp; j++) csr[base + excl + j] = N_NODES;  // <=3 pads/node
}

// ---------------- fused GIN layer: agg -> GEMM1 -> relu -> GEMM2 -> relu ----------------
// One wave per block, 32 rows per wave. Phase 1 aggregates the 32 node rows
// (t = x_i + sum x_j; R3-style: lane = dword of the 256 B row, unroll-8, %4-padded
// CSR with zero sentinel row) straight into the wave-private LDS A-tile at stride
// 136 shorts -- the exact layout GEMM1's A-fragment ds_reads expect (same pattern
// as the verified GEMM2 u-read). Then the 2-strip MFMA pipeline runs unchanged,
// u-staging reusing the same LDS region (A-frags are in registers by then).
// No __syncthreads anywhere: all LDS is wave-private. Kills the P round-trip
// (25.6 MB write + 25.6 MB read per layer) and 3 dispatches.

template <bool OUT_F32>
__global__ __launch_bounds__(64, 3) void gin_layer(const unsigned int* __restrict__ xbu,
                                                   const int* __restrict__ off,
                                                   const int* __restrict__ csr,
                                                   const unsigned short* __restrict__ W1t,
                                                   const float* __restrict__ bias1,
                                                   const unsigned short* __restrict__ W2t,
                                                   const float* __restrict__ bias2,
                                                   void* __restrict__ out) {
    __shared__ unsigned int smem[2176];           // 8704 B: 32 rows x 136 shorts
    int lane = threadIdx.x;                       // 0..63
    int quad = lane >> 4, mr = lane & 15;
    int m_base = blockIdx.x * 32;                 // grid 3125 -> rows cover exactly N_NODES

    // ---- phase 1: aggregate 32 rows into LDS ----
    for (int s = 0; s < 32; s++) {
        int node = m_base + s;
        unsigned int me = xbu[(size_t)node * 64 + lane];
        float ax = b2f_lo(me), ay = b2f_hi(me);
        int k = off[node], e = off[node + 1];
        for (; k + 8 <= e; k += 8) {
            int n0 = csr[k + 0], n1 = csr[k + 1], n2 = csr[k + 2], n3 = csr[k + 3];
            int n4 = csr[k + 4], n5 = csr[k + 5], n6 = csr[k + 6], n7 = csr[k + 7];
            unsigned int g0 = xbu[(size_t)n0 * 64 + lane];
            unsigned int g1 = xbu[(size_t)n1 * 64 + lane];
            unsigned int g2 = xbu[(size_t)n2 * 64 + lane];
            unsigned int g3 = xbu[(size_t)n3 * 64 + lane];
            unsigned int g4 = xbu[(size_t)n4 * 64 + lane];
            unsigned int g5 = xbu[(size_t)n5 * 64 + lane];
            unsigned int g6 = xbu[(size_t)n6 * 64 + lane];
            unsigned int g7 = xbu[(size_t)n7 * 64 + lane];
            ax += b2f_lo(g0) + b2f_lo(g1) + b2f_lo(g2) + b2f_lo(g3)
                + b2f_lo(g4) + b2f_lo(g5) + b2f_lo(g6) + b2f_lo(g7);
            ay += b2f_hi(g0) + b2f_hi(g1) + b2f_hi(g2) + b2f_hi(g3)
                + b2f_hi(g4) + b2f_hi(g5) + b2f_hi(g6) + b2f_hi(g7);
        }
        if (k < e) {   // %4 padding: remainder is exactly one 4-round
            int n0 = csr[k + 0], n1 = csr[k + 1], n2 = csr[k + 2], n3 = csr[k + 3];
            unsigned int g0 = xbu[(size_t)n0 * 64 + lane];
            unsigned int g1 = xbu[(size_t)n1 * 64 + lane];
            unsigned int g2 = xbu[(size_t)n2 * 64 + lane];
            unsigned int g3 = xbu[(size_t)n3 * 64 + lane];
            ax += b2f_lo(g0) + b2f_lo(g1) + b2f_lo(g2) + b2f_lo(g3);
            ay += b2f_hi(g0) + b2f_hi(g1) + b2f_hi(g2) + b2f_hi(g3);
        }
        smem[s * 68 + lane] = (unsigned int)f2b(ax) | ((unsigned int)f2b(ay) << 16);
    }

    unsigned short* ust = (unsigned short*)smem;

    // ---- GEMM1: u = relu(t @ W1 + b1), A-frags from LDS ----
    bf16x8 a0[4], a1[4];
#pragma unroll
    for (int kc = 0; kc < 4; kc++) {
        a0[kc] = *(const bf16x8*)&ust[mr * 136 + kc * 32 + quad * 8];
        a1[kc] = *(const bf16x8*)&ust[2176 + mr * 136 + kc * 32 + quad * 8];
    }

    f32x4 acc0[8], acc1[8];
#pragma unroll
    for (int nt = 0; nt < 8; nt++) { acc0[nt] = (f32x4)0.0f; acc1[nt] = (f32x4)0.0f; }
#pragma unroll
    for (int nt = 0; nt < 8; nt++) {
        const unsigned short* wp = W1t + (size_t)(nt * 16 + mr) * D + quad * 8;
#pragma unroll
        for (int kc = 0; kc < 4; kc++) {
            bf16x8 b = *(const bf16x8*)(wp + kc * 32);
            acc0[nt] = __builtin_amdgcn_mfma_f32_16x16x32_bf16(a0[kc], b, acc0[nt], 0, 0, 0);
            acc1[nt] = __builtin_amdgcn_mfma_f32_16x16x32_bf16(a1[kc], b, acc1[nt], 0, 0, 0);
        }
    }
    // C layout: col(n) = mr, row(m in strip) = quad*4 + r
#pragma unroll
    for (int nt = 0; nt < 8; nt++) {
        float bv = bias1[nt * 16 + mr];
#pragma unroll
        for (int r = 0; r < 4; r++) {
            ust[(quad * 4 + r) * 136 + nt * 16 + mr] = f2b(fmaxf(acc0[nt][r] + bv, 0.0f));
            ust[2176 + (quad * 4 + r) * 136 + nt * 16 + mr] = f2b(fmaxf(acc1[nt][r] + bv, 0.0f));
        }
    }

    // ---- GEMM2: y = relu(u @ W2 + b2) ----
#pragma unroll
    for (int kc = 0; kc < 4; kc++) {
        a0[kc] = *(const bf16x8*)&ust[mr * 136 + kc * 32 + quad * 8];
        a1[kc] = *(const bf16x8*)&ust[2176 + mr * 136 + kc * 32 + quad * 8];
    }
#pragma unroll
    for (int nt = 0; nt < 8; nt++) { acc0[nt] = (f32x4)0.0f; acc1[nt] = (f32x4)0.0f; }
#pragma unroll
    for (int nt = 0; nt < 8; nt++) {
        const unsigned short* wp = W2t + (size_t)(nt * 16 + mr) * D + quad * 8;
#pragma unroll
        for (int kc = 0; kc < 4; kc++) {
            bf16x8 b = *(const bf16x8*)(wp + kc * 32);
            acc0[nt] = __builtin_amdgcn_mfma_f32_16x16x32_bf16(a0[kc], b, acc0[nt], 0, 0, 0);
            acc1[nt] = __builtin_amdgcn_mfma_f32_16x16x32_bf16(a1[kc], b, acc1[nt], 0, 0, 0);
        }
    }

    // ---- epilogue: stage strips in LDS, coalesced store (A/u staging dead now) ----
    if (OUT_F32) {
        float* st = (float*)smem;   // 16 x 132 f32 = 8448 B <= 8704 B
        const int S = 132;
        float* op = (float*)out;
#pragma unroll
        for (int s = 0; s < 2; s++) {
#pragma unroll
            for (int nt = 0; nt < 8; nt++) {
                float bv = bias2[nt * 16 + mr];
#pragma unroll
                for (int r = 0; r < 4; r++) {
                    float v = s ? acc1[nt][r] : acc0[nt][r];
                    st[(quad * 4 + r) * S + nt * 16 + mr] = fmaxf(v + bv, 0.0f);
                }
            }
#pragma unroll
            for (int it = 0; it < 8; it++) {
                int linear = lane + it * 64;
                int row = linear >> 5, col = (linear & 31) << 2;
                int gm = m_base + s * 16 + row;
                if (gm < N_NODES) {
                    float4 val = *(float4*)&st[row * S + col];
                    *(float4*)(op + (size_t)gm * D + col) = val;
                }
            }
        }
    } else {
        const int S = 136;
        unsigned short* op = (unsigned short*)out;
#pragma unroll
        for (int s = 0; s < 2; s++) {
            unsigned short* st = ust + s * 2176;
#pragma unroll
            for (int nt = 0; nt < 8; nt++) {
                float bv = bias2[nt * 16 + mr];
#pragma unroll
                for (int r = 0; r < 4; r++) {
                    float v = s ? acc1[nt][r] : acc0[nt][r];
                    st[(quad * 4 + r) * S + nt * 16 + mr] = f2b(fmaxf(v + bv, 0.0f));
                }
            }
#pragma unroll
            for (int it = 0; it < 4; it++) {
                int linear = lane + it * 64;
                int row = linear >> 4, col = (linear & 15) << 3;
                int gm = m_base + s * 16 + row;
                if (gm < N_NODES) {
                    uint4 val = *(uint4*)&st[row * S + col];
                    *(uint4*)(op + (size_t)gm * D + col) = val;
                }
            }
        }
    }
}

// ---------------- launch ----------------

extern "C" void kernel_launch(void* const* d_in, const int* in_sizes, int n_in,
                              void* d_out, int out_size, void* d_ws, size_t ws_size,
                              hipStream_t stream) {
    const float* x = (const float*)d_in[0];
    const int* ei = (const int*)d_in[1];
    const int* srcv = ei;
    const int* dstv = ei + N_EDGES;
    const float* W1[3] = {(const float*)d_in[2], (const float*)d_in[6], (const float*)d_in[10]};
    const float* b1[3] = {(const float*)d_in[3], (const float*)d_in[7], (const float*)d_in[11]};
    const float* W2[3] = {(const float*)d_in[4], (const float*)d_in[8], (const float*)d_in[12]};
    const float* b2[3] = {(const float*)d_in[5], (const float*)d_in[9], (const float*)d_in[13]};

    // ws layout (high-water 59,397,136 <= previous 59,398,400):
    char* ws = (char*)d_ws;
    int* off = (int*)ws;                                     // (N+1) ints @ 0 .. 400,004
    unsigned short* Wt[6];                                   // 6 x 32KB @ 400,016
    for (int i = 0; i < 6; i++) Wt[i] = (unsigned short*)(ws + 400016 + i * 32768);
    unsigned short* xb0 = (unsigned short*)(ws + 596624);    // (N+1)*256 B, sentinel row N
    unsigned short* xb1 = (unsigned short*)(ws + 26196880);  // (N+1)*256 B, sentinel row N
    int* csr = (int*)(ws + 51797136);                        // padded CSR <= E+3N ints = 7.6MB

    // d_out scratch (dead before the final layer writes d_out; final layer reads
    // only off/csr/xb0 which live in ws):
    char* dob = (char*)d_out;
    int* bcur  = (int*)(dob);               // NBUCK ints (zeroed by prep)
    int* deg   = (int*)(dob + 4096);        // N ints
    int* ptot  = (int*)(dob + 450560);      // NBUCK ints
    int* bbase = (int*)(dob + 454656);      // NBUCK ints
    u64* ebuf  = (u64*)(dob + 1048576);     // NBUCK*CAP u64 = 16.06MB, ends 17,104,896

    // --- prep: zero bcur + both sentinel rows + convert weights + convert x -> xb0 ---
    prep_kernel<<<12885, 256, 0, stream>>>(
        x, xb0,
        W1[0], W2[0], W1[1], W2[1], W1[2], W2[2],
        Wt[0], Wt[1], Wt[2], Wt[3], Wt[4], Wt[5],
        (uint4*)dob,
        (uint4*)(xb0 + (size_t)N_NODES * D),
        (uint4*)(xb1 + (size_t)N_NODES * D));

    // --- CSR build (bucket-local, padded to %4 per node) ---
    bin_kernel<<<782, 256, 0, stream>>>(srcv, dstv, bcur, ebuf);
    bucket_hist_kernel<<<NBUCK, 1024, 0, stream>>>(ebuf, bcur, deg, ptot);
    pscan_kernel<<<1, 128, 0, stream>>>(ptot, bbase, off);
    bucket_csr_kernel<<<NBUCK, 1024, 0, stream>>>(ebuf, bcur, deg, bbase, off, csr);

    const int grid = N_NODES / 32;   // 3125, exact cover

    // fused layers, ping-pong xb0/xb1
    gin_layer<false><<<grid, 64, 0, stream>>>((const unsigned int*)xb0, off, csr,
                                              Wt[0], b1[0], Wt[1], b2[0], xb1);
    gin_layer<false><<<grid, 64, 0, stream>>>((const unsigned int*)xb1, off, csr,
                                              Wt[2], b1[1], Wt[3], b2[1], xb0);
    gin_layer<true><<<grid, 64, 0, stream>>>((const unsigned int*)xb0, off, csr,
                                             Wt[4], b1[2], Wt[5], b2[2], d_out);
}

// Round 7
// 488.776 us; speedup vs baseline: 1.2689x; 1.2689x over previous
//
#include <hip/hip_runtime.h>

#define N_NODES 100000
#define N_EDGES 1600000
#define D 128
#define NBUCK 98          // ceil(N_NODES / 1024), bucket = dst >> 10
#define CAP 20480         // ebuf slab capacity per bucket (raw edges); mean 16384, sigma~127
#define PCAP 24576        // csr slab capacity per bucket (padded); max = CAP + 3*1024 = 23552

typedef __attribute__((ext_vector_type(8))) short bf16x8;
typedef __attribute__((ext_vector_type(4))) float f32x4;
typedef unsigned long long u64;

__device__ __forceinline__ float b2f_lo(unsigned int u) {
    return __builtin_bit_cast(float, u << 16);
}
__device__ __forceinline__ float b2f_hi(unsigned int u) {
    return __builtin_bit_cast(float, u & 0xFFFF0000u);
}
__device__ __forceinline__ unsigned short f2b(float f) {
    unsigned int u = __builtin_bit_cast(unsigned int, f);
    u += 0x7FFFu + ((u >> 16) & 1u);
    return (unsigned short)(u >> 16);
}

// ---------------- prep: zero scratch + convert weights + convert x (row-major) ----------------

__global__ __launch_bounds__(256) void prep_kernel(
    const float* __restrict__ x, unsigned short* __restrict__ xb,
    const float* __restrict__ W0, const float* __restrict__ W1_, const float* __restrict__ W2_,
    const float* __restrict__ W3, const float* __restrict__ W4, const float* __restrict__ W5,
    unsigned short* __restrict__ T0, unsigned short* __restrict__ T1_,
    unsigned short* __restrict__ T2_, unsigned short* __restrict__ T3,
    unsigned short* __restrict__ T4, unsigned short* __restrict__ T5,
    uint4* __restrict__ dob4, uint4* __restrict__ xs0) {
    int blk = blockIdx.x;
    if (blk < 384) {
        const float* W;
        unsigned short* T;
        switch (blk >> 6) {
            case 0: W = W0; T = T0; break;
            case 1: W = W1_; T = T1_; break;
            case 2: W = W2_; T = T2_; break;
            case 3: W = W3; T = T3; break;
            case 4: W = W4; T = T4; break;
            default: W = W5; T = T5; break;
        }
        int i = (blk & 63) * 256 + threadIdx.x;   // 0..16383
        int k = i >> 7, n = i & 127;
        T[n * 128 + k] = f2b(W[i]);               // [k][n] fp32 -> [n][k] bf16
    } else if (blk < 12884) {
        int i = (blk - 384) * 256 + threadIdx.x;  // float4 chunks, 3,200,000 total
        if (i < 3200000) {
            float4 v = ((const float4*)x)[i];
            ushort4 o;
            o.x = f2b(v.x); o.y = f2b(v.y); o.z = f2b(v.z); o.w = f2b(v.w);
            ((ushort4*)xb)[i] = o;
        }
    } else {
        int i = (blk - 12884) * 256 + threadIdx.x;
        uint4 z = {0u, 0u, 0u, 0u};
        if (i < 256) dob4[i] = z;     // zero d_out scratch head (bcur)
        if (i < 16) xs0[i] = z;       // zero sentinel row xb[N_NODES]
    }
}

// ---------------- CSR build (bucket-local, LDS atomics only, degrees padded to %4) ----------------

// Bin edges into fixed-stride bucket slabs: slab b = ebuf[b*CAP ...].
__global__ __launch_bounds__(256) void bin_kernel(const int* __restrict__ src,
                                                  const int* __restrict__ dst,
                                                  int* __restrict__ bcur,
                                                  u64* __restrict__ ebuf) {
    __shared__ int h[NBUCK];
    __shared__ int base[NBUCK];
    int tid = threadIdx.x;
    if (tid < NBUCK) h[tid] = 0;
    __syncthreads();
    int e0 = blockIdx.x * 2048;
    int myd[8], mys[8];
#pragma unroll
    for (int i = 0; i < 8; i++) {
        int e = e0 + tid + i * 256;
        int dv = (e < N_EDGES) ? dst[e] : -1;
        myd[i] = dv;
        mys[i] = (e < N_EDGES) ? src[e] : 0;
        if (dv >= 0) atomicAdd(&h[dv >> 10], 1);
    }
    __syncthreads();
    if (tid < NBUCK) {
        int c = h[tid];
        base[tid] = (c > 0) ? (tid * CAP + atomicAdd(&bcur[tid], c)) : 0;
        h[tid] = 0;
    }
    __syncthreads();
#pragma unroll
    for (int i = 0; i < 8; i++) {
        int dv = myd[i];
        if (dv >= 0) {
            int b = dv >> 10;
            int p = base[b] + atomicAdd(&h[b], 1);
            if (p < (b + 1) * CAP)
                ebuf[p] = ((u64)(unsigned int)dv << 32) | (unsigned int)mys[i];
        }
    }
}

// One kernel per bucket: LDS hist -> padded LDS scan -> off/offe -> LDS-atomic
// scatter into the bucket's fixed-stride csr slab -> sentinel pads. Replaces the
// bucket_hist + pscan + bucket_csr trio (fixed-stride slabs remove the need for
// globally contiguous offsets; agg reads [off, offe) so inter-bucket gaps are
// never touched). All atomics are LDS; csr writes land in a contiguous ~96KB
// window per block.
__global__ __launch_bounds__(1024) void bucket_all_kernel(const u64* __restrict__ ebuf,
                                                          const int* __restrict__ bcur,
                                                          int* __restrict__ off,
                                                          int* __restrict__ offe,
                                                          int* __restrict__ csr) {
    __shared__ int hist[1024];
    __shared__ int sc[1024];
    __shared__ int cnt[1024];
    int b = blockIdx.x, tid = threadIdx.x;
    int nE = bcur[b]; if (nE > CAP) nE = CAP;
    int base = b * PCAP;
    const u64* slab = ebuf + (size_t)b * CAP;
    hist[tid] = 0;
    cnt[tid] = 0;
    __syncthreads();
    for (int i = tid; i < nE; i += 1024)
        atomicAdd(&hist[(int)(slab[i] >> 32) & 1023], 1);
    __syncthreads();
    int node = b * 1024 + tid;
    int d = hist[tid];
    int dp = (node < N_NODES) ? ((d + 3) & ~3) : 0;
    sc[tid] = dp;
    __syncthreads();
#pragma unroll
    for (int s = 1; s < 1024; s <<= 1) {
        int t = (tid >= s) ? sc[tid - s] : 0;
        __syncthreads();
        sc[tid] += t;
        __syncthreads();
    }
    int excl = sc[tid] - dp;
    sc[tid] = excl;
    if (node < N_NODES) {
        off[node] = base + excl;
        offe[node] = base + excl + dp;
    }
    __syncthreads();
    for (int i = tid; i < nE; i += 1024) {
        u64 e = slab[i];
        int dd = (int)(e >> 32) & 1023;
        int pos = sc[dd] + atomicAdd(&cnt[dd], 1);
        csr[base + pos] = (int)(e & 0xFFFFFFFFu);
    }
    for (int j = d; j < dp; j++) csr[base + excl + j] = N_NODES;  // <=3 pads/node
}

// ---------------- aggregation: t[i] = x[i] + sum_{j in N_in(i)} x[j]  (bf16 in/out) ----------------
// R3 form (best measured: 62.4us): 1 node/wave, lane = dword of the 256B row,
// unroll-8 dword gathers. %4-padded CSR -> remainder is exactly one 4-round
// (sentinel row N_NODES is zero, L1-resident).

__global__ __launch_bounds__(256) void agg_bf16(const unsigned int* __restrict__ xb,
                                                const int* __restrict__ off,
                                                const int* __restrict__ offe,
                                                const int* __restrict__ csr,
                                                unsigned int* __restrict__ t) {
    int node = blockIdx.x * 4 + (threadIdx.x >> 6);
    int lane = threadIdx.x & 63;
    unsigned int v = xb[(size_t)node * 64 + lane];
    float ax = b2f_lo(v), ay = b2f_hi(v);
    int k = off[node], e = offe[node];
    for (; k + 8 <= e; k += 8) {
        int n0 = csr[k + 0], n1 = csr[k + 1], n2 = csr[k + 2], n3 = csr[k + 3];
        int n4 = csr[k + 4], n5 = csr[k + 5], n6 = csr[k + 6], n7 = csr[k + 7];
        unsigned int g0 = xb[(size_t)n0 * 64 + lane];
        unsigned int g1 = xb[(size_t)n1 * 64 + lane];
        unsigned int g2 = xb[(size_t)n2 * 64 + lane];
        unsigned int g3 = xb[(size_t)n3 * 64 + lane];
        unsigned int g4 = xb[(size_t)n4 * 64 + lane];
        unsigned int g5 = xb[(size_t)n5 * 64 + lane];
        unsigned int g6 = xb[(size_t)n6 * 64 + lane];
        unsigned int g7 = xb[(size_t)n7 * 64 + lane];
        ax += b2f_lo(g0) + b2f_lo(g1) + b2f_lo(g2) + b2f_lo(g3)
            + b2f_lo(g4) + b2f_lo(g5) + b2f_lo(g6) + b2f_lo(g7);
        ay += b2f_hi(g0) + b2f_hi(g1) + b2f_hi(g2) + b2f_hi(g3)
            + b2f_hi(g4) + b2f_hi(g5) + b2f_hi(g6) + b2f_hi(g7);
    }
    if (k < e) {   // padded %4: remainder is exactly one 4-round
        int n0 = csr[k + 0], n1 = csr[k + 1], n2 = csr[k + 2], n3 = csr[k + 3];
        unsigned int g0 = xb[(size_t)n0 * 64 + lane];
        unsigned int g1 = xb[(size_t)n1 * 64 + lane];
        unsigned int g2 = xb[(size_t)n2 * 64 + lane];
        unsigned int g3 = xb[(size_t)n3 * 64 + lane];
        ax += b2f_lo(g0) + b2f_lo(g1) + b2f_lo(g2) + b2f_lo(g3);
        ay += b2f_hi(g0) + b2f_hi(g1) + b2f_hi(g2) + b2f_hi(g3);
    }
    t[(size_t)node * 64 + lane] = (unsigned int)f2b(ax) | ((unsigned int)f2b(ay) << 16);
}

// ---------------- fused MLP: y = relu(relu(t @ W1 + b1) @ W2 + b2) ----------------
// 2 row-strips (32 rows) per wave: one W-fragment load feeds MFMAs of both strips.
// Per-wave LDS 8704 B (u-strips; epilogue reuses the region).

template <bool OUT_F32>
__global__ __launch_bounds__(256) void mlp_mfma(const unsigned short* __restrict__ A,
                                                const unsigned short* __restrict__ W1t,
                                                const float* __restrict__ bias1,
                                                const unsigned short* __restrict__ W2t,
                                                const float* __restrict__ bias2,
                                                void* __restrict__ out) {
    __shared__ char smem[4 * 8704];
    int tid = threadIdx.x;
    int wave = tid >> 6, lane = tid & 63;
    int quad = lane >> 4, mr = lane & 15;
    int m_base = blockIdx.x * 128 + wave * 32;
    int m0 = m_base + mr;       if (m0 >= N_NODES) m0 = N_NODES - 1;
    int m1 = m_base + 16 + mr;  if (m1 >= N_NODES) m1 = N_NODES - 1;

    unsigned short* ust = (unsigned short*)(smem + wave * 8704);  // strip0 @0, strip1 @2176 shorts

    // ---- GEMM1: u = relu(t @ W1 + b1), both strips ----
    bf16x8 a0[4], a1[4];
#pragma unroll
    for (int kc = 0; kc < 4; kc++) {
        a0[kc] = *(const bf16x8*)(A + (size_t)m0 * D + kc * 32 + quad * 8);
        a1[kc] = *(const bf16x8*)(A + (size_t)m1 * D + kc * 32 + quad * 8);
    }

    f32x4 acc0[8], acc1[8];
#pragma unroll
    for (int nt = 0; nt < 8; nt++) { acc0[nt] = (f32x4)0.0f; acc1[nt] = (f32x4)0.0f; }
#pragma unroll
    for (int nt = 0; nt < 8; nt++) {
        const unsigned short* wp = W1t + (size_t)(nt * 16 + mr) * D + quad * 8;
#pragma unroll
        for (int kc = 0; kc < 4; kc++) {
            bf16x8 b = *(const bf16x8*)(wp + kc * 32);
            acc0[nt] = __builtin_amdgcn_mfma_f32_16x16x32_bf16(a0[kc], b, acc0[nt], 0, 0, 0);
            acc1[nt] = __builtin_amdgcn_mfma_f32_16x16x32_bf16(a1[kc], b, acc1[nt], 0, 0, 0);
        }
    }
    // C layout: col(n) = mr, row(m in strip) = quad*4 + r
#pragma unroll
    for (int nt = 0; nt < 8; nt++) {
        float bv = bias1[nt * 16 + mr];
#pragma unroll
        for (int r = 0; r < 4; r++) {
            ust[(quad * 4 + r) * 136 + nt * 16 + mr] = f2b(fmaxf(acc0[nt][r] + bv, 0.0f));
            ust[2176 + (quad * 4 + r) * 136 + nt * 16 + mr] = f2b(fmaxf(acc1[nt][r] + bv, 0.0f));
        }
    }

    // ---- GEMM2: y = relu(u @ W2 + b2), both strips ----
#pragma unroll
    for (int kc = 0; kc < 4; kc++) {
        a0[kc] = *(const bf16x8*)&ust[mr * 136 + kc * 32 + quad * 8];
        a1[kc] = *(const bf16x8*)&ust[2176 + mr * 136 + kc * 32 + quad * 8];
    }
#pragma unroll
    for (int nt = 0; nt < 8; nt++) { acc0[nt] = (f32x4)0.0f; acc1[nt] = (f32x4)0.0f; }
#pragma unroll
    for (int nt = 0; nt < 8; nt++) {
        const unsigned short* wp = W2t + (size_t)(nt * 16 + mr) * D + quad * 8;
#pragma unroll
        for (int kc = 0; kc < 4; kc++) {
            bf16x8 b = *(const bf16x8*)(wp + kc * 32);
            acc0[nt] = __builtin_amdgcn_mfma_f32_16x16x32_bf16(a0[kc], b, acc0[nt], 0, 0, 0);
            acc1[nt] = __builtin_amdgcn_mfma_f32_16x16x32_bf16(a1[kc], b, acc1[nt], 0, 0, 0);
        }
    }

    // ---- epilogue: stage each strip in LDS, coalesced store (u-strips dead now) ----
    if (OUT_F32) {
        float* st = (float*)ust;   // 16 x 132 f32 = 8448 B, fits in the 8704 B wave region
        const int S = 132;
        float* op = (float*)out;
#pragma unroll
        for (int s = 0; s < 2; s++) {
#pragma unroll
            for (int nt = 0; nt < 8; nt++) {
                float bv = bias2[nt * 16 + mr];
#pragma unroll
                for (int r = 0; r < 4; r++) {
                    float v = s ? acc1[nt][r] : acc0[nt][r];
                    st[(quad * 4 + r) * S + nt * 16 + mr] = fmaxf(v + bv, 0.0f);
                }
            }
#pragma unroll
            for (int it = 0; it < 8; it++) {
                int linear = lane + it * 64;
                int row = linear >> 5, col = (linear & 31) << 2;
                int gm = m_base + s * 16 + row;
                if (gm < N_NODES) {
                    float4 val = *(float4*)&st[row * S + col];
                    *(float4*)(op + (size_t)gm * D + col) = val;
                }
            }
        }
    } else {
        const int S = 136;
        unsigned short* op = (unsigned short*)out;
#pragma unroll
        for (int s = 0; s < 2; s++) {
            unsigned short* st = ust + s * 2176;
#pragma unroll
            for (int nt = 0; nt < 8; nt++) {
                float bv = bias2[nt * 16 + mr];
#pragma unroll
                for (int r = 0; r < 4; r++) {
                    float v = s ? acc1[nt][r] : acc0[nt][r];
                    st[(quad * 4 + r) * S + nt * 16 + mr] = f2b(fmaxf(v + bv, 0.0f));
                }
            }
#pragma unroll
            for (int it = 0; it < 4; it++) {
                int linear = lane + it * 64;
                int row = linear >> 4, col = (linear & 15) << 3;
                int gm = m_base + s * 16 + row;
                if (gm < N_NODES) {
                    uint4 val = *(uint4*)&st[row * S + col];
                    *(uint4*)(op + (size_t)gm * D + col) = val;
                }
            }
        }
    }
}

// ---------------- launch ----------------

extern "C" void kernel_launch(void* const* d_in, const int* in_sizes, int n_in,
                              void* d_out, int out_size, void* d_ws, size_t ws_size,
                              hipStream_t stream) {
    const float* x = (const float*)d_in[0];
    const int* ei = (const int*)d_in[1];
    const int* srcv = ei;
    const int* dstv = ei + N_EDGES;
    const float* W1[3] = {(const float*)d_in[2], (const float*)d_in[6], (const float*)d_in[10]};
    const float* b1[3] = {(const float*)d_in[3], (const float*)d_in[7], (const float*)d_in[11]};
    const float* W2[3] = {(const float*)d_in[4], (const float*)d_in[8], (const float*)d_in[12]};
    const float* b2[3] = {(const float*)d_in[5], (const float*)d_in[9], (const float*)d_in[13]};

    // ws layout (high-water 52,248,832):
    char* ws = (char*)d_ws;
    int* off  = (int*)ws;                                    // N ints @ 0
    int* offe = (int*)(ws + 400000);                         // N ints
    unsigned short* Wt[6];                                   // 6 x 32KB @ 800,000
    for (int i = 0; i < 6; i++) Wt[i] = (unsigned short*)(ws + 800000 + i * 32768);
    unsigned short* xb = (unsigned short*)(ws + 1048576);    // (N+1)*256 B, sentinel row N
    unsigned short* P  = (unsigned short*)(ws + 26648832);   // N*256 B, ends 52,248,832

    // d_out scratch (all dead before the final mlp writes d_out: bcur ends at bin,
    // ebuf at bucket_all, csr/off reads at agg-3 which precedes mlp-3):
    char* dob = (char*)d_out;
    int* bcur = (int*)(dob);                // NBUCK ints (zeroed by prep)
    u64* ebuf = (u64*)(dob + 1048576);      // NBUCK*CAP u64 = 16.06MB, ends 17,104,896
    int* csr  = (int*)(dob + 17104896);     // NBUCK*PCAP ints = 9.63MB, ends 26,738,688

    // --- prep: zero bcur + sentinel row + convert weights + convert x -> xb ---
    prep_kernel<<<12885, 256, 0, stream>>>(
        x, xb,
        W1[0], W2[0], W1[1], W2[1], W1[2], W2[2],
        Wt[0], Wt[1], Wt[2], Wt[3], Wt[4], Wt[5],
        (uint4*)dob, (uint4*)(xb + (size_t)N_NODES * D));

    // --- CSR build: 2 kernels (bin -> fused hist/scan/scatter per bucket) ---
    bin_kernel<<<782, 256, 0, stream>>>(srcv, dstv, bcur, ebuf);
    bucket_all_kernel<<<NBUCK, 1024, 0, stream>>>(ebuf, bcur, off, offe, csr);

    const int agg_grid = 25000;                        // 4 nodes/block, 1 node/wave
    const int mlp_grid = (N_NODES + 127) / 128;        // 782 (2 strips/wave)

    // layer 0: agg xb->P, mlp P->xb
    agg_bf16<<<agg_grid, 256, 0, stream>>>((const unsigned int*)xb, off, offe, csr, (unsigned int*)P);
    mlp_mfma<false><<<mlp_grid, 256, 0, stream>>>(P, Wt[0], b1[0], Wt[1], b2[0], xb);
    // layer 1
    agg_bf16<<<agg_grid, 256, 0, stream>>>((const unsigned int*)xb, off, offe, csr, (unsigned int*)P);
    mlp_mfma<false><<<mlp_grid, 256, 0, stream>>>(P, Wt[2], b1[1], Wt[3], b2[1], xb);
    // layer 2
    agg_bf16<<<agg_grid, 256, 0, stream>>>((const unsigned int*)xb, off, offe, csr, (unsigned int*)P);
    mlp_mfma<true><<<mlp_grid, 256, 0, stream>>>(P, Wt[4], b1[2], Wt[5], b2[2], d_out);
}

// Round 8
// 414.458 us; speedup vs baseline: 1.4965x; 1.1793x over previous
//
#include <hip/hip_runtime.h>

#define N_NODES 100000
#define N_EDGES 1600000
#define D 128
#define NBUCK 98          // ceil(N_NODES / 1024), bucket = dst >> 10
#define CAP 20480         // ebuf slab capacity per bucket (raw edges); mean 16384, sigma~127
#define PCAP 24576        // csr slab capacity per bucket (padded); max = CAP + 3*1024 = 23552

typedef __attribute__((ext_vector_type(8))) short bf16x8;
typedef __attribute__((ext_vector_type(4))) float f32x4;
typedef unsigned long long u64;

__device__ __forceinline__ float b2f_lo(unsigned int u) {
    return __builtin_bit_cast(float, u << 16);
}
__device__ __forceinline__ float b2f_hi(unsigned int u) {
    return __builtin_bit_cast(float, u & 0xFFFF0000u);
}
__device__ __forceinline__ unsigned short f2b(float f) {
    unsigned int u = __builtin_bit_cast(unsigned int, f);
    u += 0x7FFFu + ((u >> 16) & 1u);
    return (unsigned short)(u >> 16);
}

// ---------------- prep: zero scratch + weights -> MFMA-fragment order + convert x ----------------
// Wf layout (shorts): [((nt*4+kc)*64 + lane)*8 + j], lane = quad*16+mr. Each mlp
// b-load is then ONE contiguous 1KB wave-read (was 16 lanes x 16B at 256B stride =
// 16 scattered cache lines per instruction -- the mlp stall source).

__global__ __launch_bounds__(256) void prep_kernel(
    const float* __restrict__ x, unsigned short* __restrict__ xb,
    const float* __restrict__ W0, const float* __restrict__ W1_, const float* __restrict__ W2_,
    const float* __restrict__ W3, const float* __restrict__ W4, const float* __restrict__ W5,
    unsigned short* __restrict__ T0, unsigned short* __restrict__ T1_,
    unsigned short* __restrict__ T2_, unsigned short* __restrict__ T3,
    unsigned short* __restrict__ T4, unsigned short* __restrict__ T5,
    uint4* __restrict__ dob4, uint4* __restrict__ xs0) {
    int blk = blockIdx.x;
    if (blk < 384) {
        const float* W;
        unsigned short* T;
        switch (blk >> 6) {
            case 0: W = W0; T = T0; break;
            case 1: W = W1_; T = T1_; break;
            case 2: W = W2_; T = T2_; break;
            case 3: W = W3; T = T3; break;
            case 4: W = W4; T = T4; break;
            default: W = W5; T = T5; break;
        }
        int i = (blk & 63) * 256 + threadIdx.x;   // 0..16383, i = k*128 + n
        int k = i >> 7, n = i & 127;
        int nt = n >> 4, mr = n & 15;
        int kc = k >> 5, rem = k & 31, quad = rem >> 3, j = rem & 7;
        T[(nt * 4 + kc) * 512 + quad * 128 + mr * 8 + j] = f2b(W[i]);
    } else if (blk < 12884) {
        int i = (blk - 384) * 256 + threadIdx.x;  // float4 chunks, 3,200,000 total
        if (i < 3200000) {
            float4 v = ((const float4*)x)[i];
            ushort4 o;
            o.x = f2b(v.x); o.y = f2b(v.y); o.z = f2b(v.z); o.w = f2b(v.w);
            ((ushort4*)xb)[i] = o;
        }
    } else {
        int i = (blk - 12884) * 256 + threadIdx.x;
        uint4 z = {0u, 0u, 0u, 0u};
        if (i < 256) dob4[i] = z;     // zero d_out scratch head (bcur)
        if (i < 16) xs0[i] = z;       // zero sentinel row xb[N_NODES]
    }
}

// ---------------- CSR build (bucket-local, LDS atomics only, degrees padded to %4) ----------------

__global__ __launch_bounds__(256) void bin_kernel(const int* __restrict__ src,
                                                  const int* __restrict__ dst,
                                                  int* __restrict__ bcur,
                                                  u64* __restrict__ ebuf) {
    __shared__ int h[NBUCK];
    __shared__ int base[NBUCK];
    int tid = threadIdx.x;
    if (tid < NBUCK) h[tid] = 0;
    __syncthreads();
    int e0 = blockIdx.x * 2048;
    int myd[8], mys[8];
#pragma unroll
    for (int i = 0; i < 8; i++) {
        int e = e0 + tid + i * 256;
        int dv = (e < N_EDGES) ? dst[e] : -1;
        myd[i] = dv;
        mys[i] = (e < N_EDGES) ? src[e] : 0;
        if (dv >= 0) atomicAdd(&h[dv >> 10], 1);
    }
    __syncthreads();
    if (tid < NBUCK) {
        int c = h[tid];
        base[tid] = (c > 0) ? (tid * CAP + atomicAdd(&bcur[tid], c)) : 0;
        h[tid] = 0;
    }
    __syncthreads();
#pragma unroll
    for (int i = 0; i < 8; i++) {
        int dv = myd[i];
        if (dv >= 0) {
            int b = dv >> 10;
            int p = base[b] + atomicAdd(&h[b], 1);
            if (p < (b + 1) * CAP)
                ebuf[p] = ((u64)(unsigned int)dv << 32) | (unsigned int)mys[i];
        }
    }
}

// One kernel per bucket: LDS hist -> padded LDS scan -> off/offe -> LDS-atomic
// scatter into the bucket's fixed-stride csr slab -> sentinel pads.
__global__ __launch_bounds__(1024) void bucket_all_kernel(const u64* __restrict__ ebuf,
                                                          const int* __restrict__ bcur,
                                                          int* __restrict__ off,
                                                          int* __restrict__ offe,
                                                          int* __restrict__ csr) {
    __shared__ int hist[1024];
    __shared__ int sc[1024];
    __shared__ int cnt[1024];
    int b = blockIdx.x, tid = threadIdx.x;
    int nE = bcur[b]; if (nE > CAP) nE = CAP;
    int base = b * PCAP;
    const u64* slab = ebuf + (size_t)b * CAP;
    hist[tid] = 0;
    cnt[tid] = 0;
    __syncthreads();
    for (int i = tid; i < nE; i += 1024)
        atomicAdd(&hist[(int)(slab[i] >> 32) & 1023], 1);
    __syncthreads();
    int node = b * 1024 + tid;
    int d = hist[tid];
    int dp = (node < N_NODES) ? ((d + 3) & ~3) : 0;
    sc[tid] = dp;
    __syncthreads();
#pragma unroll
    for (int s = 1; s < 1024; s <<= 1) {
        int t = (tid >= s) ? sc[tid - s] : 0;
        __syncthreads();
        sc[tid] += t;
        __syncthreads();
    }
    int excl = sc[tid] - dp;
    sc[tid] = excl;
    if (node < N_NODES) {
        off[node] = base + excl;
        offe[node] = base + excl + dp;
    }
    __syncthreads();
    for (int i = tid; i < nE; i += 1024) {
        u64 e = slab[i];
        int dd = (int)(e >> 32) & 1023;
        int pos = sc[dd] + atomicAdd(&cnt[dd], 1);
        csr[base + pos] = (int)(e & 0xFFFFFFFFu);
    }
    for (int j = d; j < dp; j++) csr[base + excl + j] = N_NODES;  // <=3 pads/node
}

// ---------------- aggregation: t[i] = x[i] + sum_{j in N_in(i)} x[j]  (bf16 in/out) ----------------
// 1 node/wave, lane = dword of the 256B row. Main loop 16 gathers in flight
// (was 8; VALUBusy 43%, no pipe saturated -> deepen ILP), 8- and 4-round tails.
// %4-padded CSR, sentinel row N_NODES is zero.

__global__ __launch_bounds__(256) void agg_bf16(const unsigned int* __restrict__ xb,
                                                const int* __restrict__ off,
                                                const int* __restrict__ offe,
                                                const int* __restrict__ csr,
                                                unsigned int* __restrict__ t) {
    int node = blockIdx.x * 4 + (threadIdx.x >> 6);
    int lane = threadIdx.x & 63;
    unsigned int v = xb[(size_t)node * 64 + lane];
    float ax = b2f_lo(v), ay = b2f_hi(v);
    int k = off[node], e = offe[node];
    for (; k + 16 <= e; k += 16) {
        int idx[16];
        unsigned int g[16];
#pragma unroll
        for (int i = 0; i < 16; i++) idx[i] = csr[k + i];
#pragma unroll
        for (int i = 0; i < 16; i++) g[i] = xb[(size_t)idx[i] * 64 + lane];
#pragma unroll
        for (int i = 0; i < 16; i++) { ax += b2f_lo(g[i]); ay += b2f_hi(g[i]); }
    }
    if (k + 8 <= e) {
        int idx[8];
        unsigned int g[8];
#pragma unroll
        for (int i = 0; i < 8; i++) idx[i] = csr[k + i];
#pragma unroll
        for (int i = 0; i < 8; i++) g[i] = xb[(size_t)idx[i] * 64 + lane];
#pragma unroll
        for (int i = 0; i < 8; i++) { ax += b2f_lo(g[i]); ay += b2f_hi(g[i]); }
        k += 8;
    }
    if (k < e) {   // padded %4: remainder is exactly one 4-round
        int idx[4];
        unsigned int g[4];
#pragma unroll
        for (int i = 0; i < 4; i++) idx[i] = csr[k + i];
#pragma unroll
        for (int i = 0; i < 4; i++) g[i] = xb[(size_t)idx[i] * 64 + lane];
#pragma unroll
        for (int i = 0; i < 4; i++) { ax += b2f_lo(g[i]); ay += b2f_hi(g[i]); }
    }
    t[(size_t)node * 64 + lane] = (unsigned int)f2b(ax) | ((unsigned int)f2b(ay) << 16);
}

// ---------------- fused MLP: y = relu(relu(t @ W1 + b1) @ W2 + b2) ----------------
// 2 row-strips (32 rows) per wave; W in fragment order -> every b-load is one
// contiguous 1KB wave-read: b = Wf[(nt*4+kc)*512 + lane*8 ..]. 128-thr blocks
// (64 rows, grid 1563) cut the 782-on-256-CU imbalance (33% -> ~17% tail).

template <bool OUT_F32>
__global__ __launch_bounds__(128) void mlp_mfma(const unsigned short* __restrict__ A,
                                                const unsigned short* __restrict__ W1f,
                                                const float* __restrict__ bias1,
                                                const unsigned short* __restrict__ W2f,
                                                const float* __restrict__ bias2,
                                                void* __restrict__ out) {
    __shared__ char smem[2 * 8704];
    int tid = threadIdx.x;
    int wave = tid >> 6, lane = tid & 63;
    int quad = lane >> 4, mr = lane & 15;
    int m_base = blockIdx.x * 64 + wave * 32;
    int m0 = m_base + mr;       if (m0 >= N_NODES) m0 = N_NODES - 1;
    int m1 = m_base + 16 + mr;  if (m1 >= N_NODES) m1 = N_NODES - 1;

    unsigned short* ust = (unsigned short*)(smem + wave * 8704);  // strip0 @0, strip1 @2176 shorts

    // ---- GEMM1: u = relu(t @ W1 + b1), both strips ----
    bf16x8 a0[4], a1[4];
#pragma unroll
    for (int kc = 0; kc < 4; kc++) {
        a0[kc] = *(const bf16x8*)(A + (size_t)m0 * D + kc * 32 + quad * 8);
        a1[kc] = *(const bf16x8*)(A + (size_t)m1 * D + kc * 32 + quad * 8);
    }

    f32x4 acc0[8], acc1[8];
#pragma unroll
    for (int nt = 0; nt < 8; nt++) { acc0[nt] = (f32x4)0.0f; acc1[nt] = (f32x4)0.0f; }
#pragma unroll
    for (int nt = 0; nt < 8; nt++) {
#pragma unroll
        for (int kc = 0; kc < 4; kc++) {
            bf16x8 b = *(const bf16x8*)(W1f + (nt * 4 + kc) * 512 + lane * 8);
            acc0[nt] = __builtin_amdgcn_mfma_f32_16x16x32_bf16(a0[kc], b, acc0[nt], 0, 0, 0);
            acc1[nt] = __builtin_amdgcn_mfma_f32_16x16x32_bf16(a1[kc], b, acc1[nt], 0, 0, 0);
        }
    }
    // C layout: col(n) = mr, row(m in strip) = quad*4 + r
#pragma unroll
    for (int nt = 0; nt < 8; nt++) {
        float bv = bias1[nt * 16 + mr];
#pragma unroll
        for (int r = 0; r < 4; r++) {
            ust[(quad * 4 + r) * 136 + nt * 16 + mr] = f2b(fmaxf(acc0[nt][r] + bv, 0.0f));
            ust[2176 + (quad * 4 + r) * 136 + nt * 16 + mr] = f2b(fmaxf(acc1[nt][r] + bv, 0.0f));
        }
    }

    // ---- GEMM2: y = relu(u @ W2 + b2), both strips ----
#pragma unroll
    for (int kc = 0; kc < 4; kc++) {
        a0[kc] = *(const bf16x8*)&ust[mr * 136 + kc * 32 + quad * 8];
        a1[kc] = *(const bf16x8*)&ust[2176 + mr * 136 + kc * 32 + quad * 8];
    }
#pragma unroll
    for (int nt = 0; nt < 8; nt++) { acc0[nt] = (f32x4)0.0f; acc1[nt] = (f32x4)0.0f; }
#pragma unroll
    for (int nt = 0; nt < 8; nt++) {
#pragma unroll
        for (int kc = 0; kc < 4; kc++) {
            bf16x8 b = *(const bf16x8*)(W2f + (nt * 4 + kc) * 512 + lane * 8);
            acc0[nt] = __builtin_amdgcn_mfma_f32_16x16x32_bf16(a0[kc], b, acc0[nt], 0, 0, 0);
            acc1[nt] = __builtin_amdgcn_mfma_f32_16x16x32_bf16(a1[kc], b, acc1[nt], 0, 0, 0);
        }
    }

    // ---- epilogue: stage each strip in LDS, coalesced store (u-strips dead now) ----
    if (OUT_F32) {
        float* st = (float*)ust;   // 16 x 132 f32 = 8448 B, fits in the 8704 B wave region
        const int S = 132;
        float* op = (float*)out;
#pragma unroll
        for (int s = 0; s < 2; s++) {
#pragma unroll
            for (int nt = 0; nt < 8; nt++) {
                float bv = bias2[nt * 16 + mr];
#pragma unroll
                for (int r = 0; r < 4; r++) {
                    float v = s ? acc1[nt][r] : acc0[nt][r];
                    st[(quad * 4 + r) * S + nt * 16 + mr] = fmaxf(v + bv, 0.0f);
                }
            }
#pragma unroll
            for (int it = 0; it < 8; it++) {
                int linear = lane + it * 64;
                int row = linear >> 5, col = (linear & 31) << 2;
                int gm = m_base + s * 16 + row;
                if (gm < N_NODES) {
                    float4 val = *(float4*)&st[row * S + col];
                    *(float4*)(op + (size_t)gm * D + col) = val;
                }
            }
        }
    } else {
        const int S = 136;
        unsigned short* op = (unsigned short*)out;
#pragma unroll
        for (int s = 0; s < 2; s++) {
            unsigned short* st = ust + s * 2176;
#pragma unroll
            for (int nt = 0; nt < 8; nt++) {
                float bv = bias2[nt * 16 + mr];
#pragma unroll
                for (int r = 0; r < 4; r++) {
                    float v = s ? acc1[nt][r] : acc0[nt][r];
                    st[(quad * 4 + r) * S + nt * 16 + mr] = f2b(fmaxf(v + bv, 0.0f));
                }
            }
#pragma unroll
            for (int it = 0; it < 4; it++) {
                int linear = lane + it * 64;
                int row = linear >> 4, col = (linear & 15) << 3;
                int gm = m_base + s * 16 + row;
                if (gm < N_NODES) {
                    uint4 val = *(uint4*)&st[row * S + col];
                    *(uint4*)(op + (size_t)gm * D + col) = val;
                }
            }
        }
    }
}

// ---------------- launch ----------------

extern "C" void kernel_launch(void* const* d_in, const int* in_sizes, int n_in,
                              void* d_out, int out_size, void* d_ws, size_t ws_size,
                              hipStream_t stream) {
    const float* x = (const float*)d_in[0];
    const int* ei = (const int*)d_in[1];
    const int* srcv = ei;
    const int* dstv = ei + N_EDGES;
    const float* W1[3] = {(const float*)d_in[2], (const float*)d_in[6], (const float*)d_in[10]};
    const float* b1[3] = {(const float*)d_in[3], (const float*)d_in[7], (const float*)d_in[11]};
    const float* W2[3] = {(const float*)d_in[4], (const float*)d_in[8], (const float*)d_in[12]};
    const float* b2[3] = {(const float*)d_in[5], (const float*)d_in[9], (const float*)d_in[13]};

    // ws layout (high-water 52,248,832):
    char* ws = (char*)d_ws;
    int* off  = (int*)ws;                                    // N ints @ 0
    int* offe = (int*)(ws + 400000);                         // N ints
    unsigned short* Wt[6];                                   // 6 x 32KB @ 800,000 (fragment order)
    for (int i = 0; i < 6; i++) Wt[i] = (unsigned short*)(ws + 800000 + i * 32768);
    unsigned short* xb = (unsigned short*)(ws + 1048576);    // (N+1)*256 B, sentinel row N
    unsigned short* P  = (unsigned short*)(ws + 26648832);   // N*256 B, ends 52,248,832

    // d_out scratch (all dead before the final mlp writes d_out):
    char* dob = (char*)d_out;
    int* bcur = (int*)(dob);                // NBUCK ints (zeroed by prep)
    u64* ebuf = (u64*)(dob + 1048576);      // NBUCK*CAP u64 = 16.06MB, ends 17,104,896
    int* csr  = (int*)(dob + 17104896);     // NBUCK*PCAP ints = 9.63MB, ends 26,738,688

    // --- prep: zero bcur + sentinel row + weights->fragment order + convert x ---
    prep_kernel<<<12885, 256, 0, stream>>>(
        x, xb,
        W1[0], W2[0], W1[1], W2[1], W1[2], W2[2],
        Wt[0], Wt[1], Wt[2], Wt[3], Wt[4], Wt[5],
        (uint4*)dob, (uint4*)(xb + (size_t)N_NODES * D));

    // --- CSR build: 2 kernels (bin -> fused hist/scan/scatter per bucket) ---
    bin_kernel<<<782, 256, 0, stream>>>(srcv, dstv, bcur, ebuf);
    bucket_all_kernel<<<NBUCK, 1024, 0, stream>>>(ebuf, bcur, off, offe, csr);

    const int agg_grid = 25000;                        // 4 nodes/block, 1 node/wave
    const int mlp_grid = 1563;                         // 64 rows/block, 2 waves

    // layer 0: agg xb->P, mlp P->xb
    agg_bf16<<<agg_grid, 256, 0, stream>>>((const unsigned int*)xb, off, offe, csr, (unsigned int*)P);
    mlp_mfma<false><<<mlp_grid, 128, 0, stream>>>(P, Wt[0], b1[0], Wt[1], b2[0], xb);
    // layer 1
    agg_bf16<<<agg_grid, 256, 0, stream>>>((const unsigned int*)xb, off, offe, csr, (unsigned int*)P);
    mlp_mfma<false><<<mlp_grid, 128, 0, stream>>>(P, Wt[2], b1[1], Wt[3], b2[1], xb);
    // layer 2
    agg_bf16<<<agg_grid, 256, 0, stream>>>((const unsigned int*)xb, off, offe, csr, (unsigned int*)P);
    mlp_mfma<true><<<mlp_grid, 128, 0, stream>>>(P, Wt[4], b1[2], Wt[5], b2[2], d_out);
}